// Round 13
// baseline (201.821 us; speedup 1.0000x reference)
//
#include <hip/hip_runtime.h>
#include <hip/hip_bf16.h>

typedef int   i32x4 __attribute__((ext_vector_type(4)));
typedef unsigned int   u32;
typedef unsigned short u16;
typedef signed char    i8;

#define TOKENS 8192
#define NDIM   4096
#define KDIM   4096
#define BK     64
#define NKT    (KDIM / BK)   // 64 K-tiles
#define SLOT   24576         // A 16KB + B 8KB

// ---------------------------------------------------------------------------
// Kernel 1 (fused, validated): blocks 0..2047 FWHT+q8; 2048..6143 qpack.
// ---------------------------------------------------------------------------
__device__ __forceinline__ u32 pack4(int4 q) {
  return (u32)(q.x & 0xff) | ((u32)(q.y & 0xff) << 8) |
         ((u32)(q.z & 0xff) << 16) | ((u32)(q.w & 0xff) << 24);
}

__global__ __launch_bounds__(256)
void fused_aux(const float* __restrict__ x, i8* __restrict__ xq,
               float* __restrict__ xscale,
               const int* __restrict__ Q, i8* __restrict__ W8) {
  if (blockIdx.x >= 2048) {
    const size_t idx = (((size_t)(blockIdx.x - 2048)) * 256 + threadIdx.x) * 16;
    int4 a = *reinterpret_cast<const int4*>(Q + idx);
    int4 b = *reinterpret_cast<const int4*>(Q + idx + 4);
    int4 c = *reinterpret_cast<const int4*>(Q + idx + 8);
    int4 d = *reinterpret_cast<const int4*>(Q + idx + 12);
    uint4 pk; pk.x = pack4(a); pk.y = pack4(b); pk.z = pack4(c); pk.w = pack4(d);
    *reinterpret_cast<uint4*>(W8 + idx) = pk;
    return;
  }
  const int row = blockIdx.x * 4 + (threadIdx.x >> 6);
  const int l   = threadIdx.x & 63;

  const float4* xv = reinterpret_cast<const float4*>(x + (size_t)row * KDIM) + l * 16;
  float v[64];
#pragma unroll
  for (int j = 0; j < 16; ++j) {
    float4 f = xv[j];
    v[4*j+0] = f.x; v[4*j+1] = f.y; v[4*j+2] = f.z; v[4*j+3] = f.w;
  }

#pragma unroll
  for (int h = 1; h < 64; h <<= 1) {
#pragma unroll
    for (int j = 0; j < 64; ++j) {
      if ((j & h) == 0) {
        float a = v[j], b = v[j + h];
        v[j] = a + b; v[j + h] = a - b;
      }
    }
  }

#pragma unroll
  for (int m = 1; m < 64; m <<= 1) {
    const bool up = (l & m) != 0;
#pragma unroll
    for (int j = 0; j < 64; ++j) {
      float p = __shfl_xor(v[j], m, 64);
      v[j] = up ? (p - v[j]) : (v[j] + p);
    }
  }

  float mxu = 0.f;
#pragma unroll
  for (int j = 0; j < 64; ++j) mxu = fmaxf(mxu, fabsf(v[j]));
#pragma unroll
  for (int m = 1; m < 64; m <<= 1) mxu = fmaxf(mxu, __shfl_xor(mxu, m, 64));
  mxu = fmaxf(mxu, 1e-30f);
  const float inv = 127.0f / mxu;

  i8* orow = xq + (size_t)row * KDIM + l * 64;
#pragma unroll
  for (int g = 0; g < 4; ++g) {
    u32 w[4];
#pragma unroll
    for (int q4 = 0; q4 < 4; ++q4) {
      int b0 = __float2int_rn(v[g*16+q4*4+0] * inv);
      int b1 = __float2int_rn(v[g*16+q4*4+1] * inv);
      int b2 = __float2int_rn(v[g*16+q4*4+2] * inv);
      int b3 = __float2int_rn(v[g*16+q4*4+3] * inv);
      b0 = min(127, max(-127, b0)); b1 = min(127, max(-127, b1));
      b2 = min(127, max(-127, b2)); b3 = min(127, max(-127, b3));
      w[q4] = (u32)(b0 & 0xff) | ((u32)(b1 & 0xff) << 8) |
              ((u32)(b2 & 0xff) << 16) | ((u32)(b3 & 0xff) << 24);
    }
    uint4 pk; pk.x = w[0]; pk.y = w[1]; pk.z = w[2]; pk.w = w[3];
    *reinterpret_cast<uint4*>(orow + g * 16) = pk;
  }
  if (l == 0) xscale[row] = mxu * (0.015625f / 127.0f);
}

// ---------------------------------------------------------------------------
// Kernel 2: int8 GEMM, TWO INDEPENDENT BLOCKS PER CU (antiphase drift).
// Block = 256 threads = 4 waves (2Mx2N), wave-tile 128x64 (acc[8][4]),
// BM=256 x BN=128, ring-2 LDS slots of 24 KB (48 KB/block, 2 blocks = 96 KB).
// Regs ~236/wave -> 8 waves/CU = 1 wave per SIMD per block: while block-0's
// wave bursts MFMA, block-1's wave on the same SIMD drains LDS reads (the
// R7-measured inter-block overlap), at R6's low LDS-traffic geometry.
// Schedule per tile (R7's proven loop): stage(t+1) -> 12 ds_read -> 16 MFMA
// (setprio) -> vmcnt(0) -> s_barrier. Verified swizzle layouts throughout.
// ---------------------------------------------------------------------------
__global__ __launch_bounds__(256, 2)
void gemm_2x4(const i8* __restrict__ A, const i8* __restrict__ B,
              const float* __restrict__ xscale, const float* __restrict__ s,
              const float* __restrict__ bias, float* __restrict__ C) {
  __shared__ __align__(16) i8 lds[2 * SLOT];   // 48 KB

  const int th   = threadIdx.x;
  const int wave = th >> 6;
  const int lane = th & 63;

  // L2-locality mapping (bijective, 1024 blocks): XCD x owns nt in {4x..4x+3}
  const int b0 = blockIdx.x;
  const int xc = b0 & 7;
  const int i  = b0 >> 3;          // 0..127
  const int mt = i >> 2;           // 0..31
  const int nt = xc * 4 + (i & 3); // 0..31

  // staging: 256 threads; A chunks j=0..3 (rows j*64+(th>>2)), B chunks j=0..1
  const int srow = th >> 2;
  const int scol = ((th & 3) * 16) ^ (((th >> 5) & 1) << 5);
  const i8* gA[4]; const i8* gB[2];
#pragma unroll
  for (int j = 0; j < 4; ++j)
    gA[j] = A + (size_t)(mt * 256 + j * 64 + srow) * KDIM + scol;
#pragma unroll
  for (int j = 0; j < 2; ++j)
    gB[j] = B + (size_t)(nt * 128 + j * 64 + srow) * KDIM + scol;
  const int ldsW = wave * 1024;   // wave-uniform base within each 4096-B chunk

#define STAGE(tt, ss) do {                                                        \
    _Pragma("unroll")                                                             \
    for (int j = 0; j < 4; ++j)                                                   \
      __builtin_amdgcn_global_load_lds(                                           \
        (const __attribute__((address_space(1))) void*)(gA[j] + (size_t)(tt) * BK), \
        (__attribute__((address_space(3))) void*)(lds + (ss) * SLOT + j * 4096 + ldsW), 16, 0, 0); \
    _Pragma("unroll")                                                             \
    for (int j = 0; j < 2; ++j)                                                   \
      __builtin_amdgcn_global_load_lds(                                           \
        (const __attribute__((address_space(1))) void*)(gB[j] + (size_t)(tt) * BK), \
        (__attribute__((address_space(3))) void*)(lds + (ss) * SLOT + 16384 + j * 4096 + ldsW), 16, 0, 0); \
  } while (0)

  // fragment byte offsets within slot (verified XOR swizzle)
  const int wm = wave >> 1;       // 0..1 -> C rows wm*128
  const int wn = wave & 1;        // 0..1 -> C cols wn*64
  const int laneRow = lane & 15;
  const int kByte   = (lane >> 4) << 4;
  const int swz     = ((lane >> 3) & 1) << 5;
  const int aOff = (((wm * 128 + laneRow) * 64 + kByte) ^ swz);          // + mi*1024
  const int bOff = (((wn * 64 + laneRow) * 64 + kByte) ^ swz) + 16384;   // + ni*1024

  i32x4 acc[8][4];
#pragma unroll
  for (int mi = 0; mi < 8; ++mi)
#pragma unroll
    for (int ni = 0; ni < 4; ++ni)
      acc[mi][ni] = i32x4{0, 0, 0, 0};

  // prologue
  STAGE(0, 0);
  asm volatile("s_waitcnt vmcnt(0)" ::: "memory");
  __builtin_amdgcn_s_barrier();

  for (int t = 0; t < NKT; ++t) {
    const char* cur = (const char*)lds + (t & 1) * SLOT;
    if (t + 1 < NKT) STAGE(t + 1, (t + 1) & 1);

    i32x4 bfr[4], af[8];
#pragma unroll
    for (int ni = 0; ni < 4; ++ni)
      bfr[ni] = *(const i32x4*)(cur + bOff + ni * 1024);
#pragma unroll
    for (int mi = 0; mi < 8; ++mi)
      af[mi] = *(const i32x4*)(cur + aOff + mi * 1024);

    __builtin_amdgcn_s_setprio(1);
#pragma unroll
    for (int mi = 0; mi < 8; ++mi)
#pragma unroll
      for (int ni = 0; ni < 4; ++ni)
        acc[mi][ni] = __builtin_amdgcn_mfma_i32_16x16x64_i8(af[mi], bfr[ni], acc[mi][ni], 0, 0, 0);
    __builtin_amdgcn_s_setprio(0);

    asm volatile("s_waitcnt vmcnt(0)" ::: "memory");
    __builtin_amdgcn_s_barrier();
  }
#undef STAGE

  // epilogue: y = acc * (xscale[row] * s[col]) + bias[col]
  const int col0 = nt * 128 + wn * 64 + (lane & 15);
  const int row0 = mt * 256 + wm * 128 + ((lane >> 4) << 2);
  float xs[4][8];
#pragma unroll
  for (int mi = 0; mi < 8; ++mi)
#pragma unroll
    for (int r = 0; r < 4; ++r)
      xs[r][mi] = xscale[row0 + mi * 16 + r];
#pragma unroll
  for (int ni = 0; ni < 4; ++ni) {
    const float sc = s[col0 + ni * 16];
    const float bv = bias[col0 + ni * 16];
#pragma unroll
    for (int mi = 0; mi < 8; ++mi) {
      float* cp = C + (size_t)(row0 + mi * 16) * NDIM + col0 + ni * 16;
#pragma unroll
      for (int r = 0; r < 4; ++r)
        cp[(size_t)r * NDIM] = (float)acc[mi][ni][r] * (xs[r][mi] * sc) + bv;
    }
  }
}

// ---------------------------------------------------------------------------
extern "C" void kernel_launch(void* const* d_in, const int* in_sizes, int n_in,
                              void* d_out, int out_size, void* d_ws, size_t ws_size,
                              hipStream_t stream) {
  (void)in_sizes; (void)n_in; (void)out_size; (void)ws_size;
  const float* x    = (const float*)d_in[0];
  const int*   Q    = (const int*)d_in[1];
  const float* s    = (const float*)d_in[2];
  const float* bias = (const float*)d_in[3];
  float* out = (float*)d_out;

  i8*    xq     = (i8*)d_ws;
  i8*    W8     = xq + (size_t)TOKENS * KDIM;
  float* xscale = (float*)(W8 + (size_t)NDIM * KDIM);

  fused_aux<<<dim3(6144), dim3(256), 0, stream>>>(x, xq, xscale, Q, W8);
  gemm_2x4<<<dim3((TOKENS / 256) * (NDIM / 128)), dim3(256), 0, stream>>>(
      xq, W8, xscale, s, bias, out);
}

// Round 14
// 193.652 us; speedup vs baseline: 1.0422x; 1.0422x over previous
//
#include <hip/hip_runtime.h>
#include <hip/hip_bf16.h>

typedef int   i32x4 __attribute__((ext_vector_type(4)));
typedef unsigned int   u32;
typedef unsigned short u16;
typedef signed char    i8;

#define TOKENS 8192
#define NDIM   4096
#define KDIM   4096
#define BK     64
#define NKT    (KDIM / BK)   // 64 K-tiles

// ---------------------------------------------------------------------------
// Kernel 1 (fused): blocks 0..2047 = FWHT+q8 (4 rows/block, 1 wave/row),
// blocks 2048..6143 = qpack. FWHT uses a padded-LDS transpose (stride 65
// words -> bank=(l+j)%32, 2-way, conflict-free both directions) so ALL 12
// butterfly stages are in-register: 128 ds_b32 replace 384 ds_bpermute.
// FP op tree identical to the shuffle version -> bitwise-identical output.
// ---------------------------------------------------------------------------
__device__ __forceinline__ u32 pack4(int4 q) {
  return (u32)(q.x & 0xff) | ((u32)(q.y & 0xff) << 8) |
         ((u32)(q.z & 0xff) << 16) | ((u32)(q.w & 0xff) << 24);
}

__global__ __launch_bounds__(256)
void fused_aux(const float* __restrict__ x, i8* __restrict__ xq,
               float* __restrict__ xscale,
               const int* __restrict__ Q, i8* __restrict__ W8) {
  __shared__ float tbuf[4 * 65 * 64];   // 4 waves x 16640 B = 66560 B

  if (blockIdx.x >= 2048) {
    // ---- qpack ----
    const size_t idx = (((size_t)(blockIdx.x - 2048)) * 256 + threadIdx.x) * 16;
    int4 a = *reinterpret_cast<const int4*>(Q + idx);
    int4 b = *reinterpret_cast<const int4*>(Q + idx + 4);
    int4 c = *reinterpret_cast<const int4*>(Q + idx + 8);
    int4 d = *reinterpret_cast<const int4*>(Q + idx + 12);
    uint4 pk; pk.x = pack4(a); pk.y = pack4(b); pk.z = pack4(c); pk.w = pack4(d);
    *reinterpret_cast<uint4*>(W8 + idx) = pk;
    return;
  }

  const int wv  = threadIdx.x >> 6;
  const int l   = threadIdx.x & 63;
  const int row = blockIdx.x * 4 + wv;
  float* lb = tbuf + wv * (65 * 64);

  // load: lane l owns elements e = l*64 + j (contiguous 64)
  const float4* xv = reinterpret_cast<const float4*>(x + (size_t)row * KDIM) + l * 16;
  float v[64];
#pragma unroll
  for (int j = 0; j < 16; ++j) {
    float4 f = xv[j];
    v[4*j+0] = f.x; v[4*j+1] = f.y; v[4*j+2] = f.z; v[4*j+3] = f.w;
  }

  // stages h=1..32 (bits 0..5 of e) in-register on j
#pragma unroll
  for (int h = 1; h < 64; h <<= 1) {
#pragma unroll
    for (int j = 0; j < 64; ++j) {
      if ((j & h) == 0) {
        float a = v[j], b = v[j + h];
        v[j] = a + b; v[j + h] = a - b;
      }
    }
  }

  // transpose via padded LDS: word (a,b) at a*65+b; write (l,j), read (j,l).
#pragma unroll
  for (int j = 0; j < 64; ++j)
    lb[l * 65 + j] = v[j];
  asm volatile("s_waitcnt lgkmcnt(0)" ::: "memory");
  __builtin_amdgcn_sched_barrier(0);
  float w[64];
#pragma unroll
  for (int j = 0; j < 64; ++j)
    w[j] = lb[j * 65 + l];
  // lane l now owns elements e = j*64 + l

  // stages h=64..2048 (bits 6..11 of e) in-register on j (h' = h/64)
#pragma unroll
  for (int h = 1; h < 64; h <<= 1) {
#pragma unroll
    for (int j = 0; j < 64; ++j) {
      if ((j & h) == 0) {
        float a = w[j], b = w[j + h];
        w[j] = a + b; w[j + h] = a - b;
      }
    }
  }

  // row absmax: local over j, then wave-reduce over l
  float mxu = 0.f;
#pragma unroll
  for (int j = 0; j < 64; ++j) mxu = fmaxf(mxu, fabsf(w[j]));
#pragma unroll
  for (int m = 1; m < 64; m <<= 1) mxu = fmaxf(mxu, __shfl_xor(mxu, m, 64));
  mxu = fmaxf(mxu, 1e-30f);
  const float inv = 127.0f / mxu;

  // quantize + store: element e = j*64 + l -> 64 coalesced 64-B byte stores
  i8* orow = xq + (size_t)row * KDIM + l;
#pragma unroll
  for (int j = 0; j < 64; ++j) {
    int b = __float2int_rn(w[j] * inv);
    b = min(127, max(-127, b));
    orow[j * 64] = (i8)b;
  }
  if (l == 0) xscale[row] = mxu * (0.015625f / 127.0f);
}

// ---------------------------------------------------------------------------
// Kernel 2: int8 GEMM — R6 register-pipeline version VERBATIM (best measured,
// 143.4 us). 256x256 tile, BK=64, 8 waves, ring-4 slots, verified swizzle,
// counted lgkm(4)/lgkm(8), vmcnt(2), one barrier/tile, bf ping-pong.
// ---------------------------------------------------------------------------
__global__ __launch_bounds__(512, 2)
void gemm256_i8(const i8* __restrict__ A, const i8* __restrict__ B,
                const float* __restrict__ xscale, const float* __restrict__ s,
                const float* __restrict__ bias, float* __restrict__ C) {
  __shared__ __align__(16) i8 lds[4 * 32768];   // 128 KB

  const int th   = threadIdx.x;
  const int wave = th >> 6;
  const int lane = th & 63;

  const int b0 = blockIdx.x;
  const int xc = b0 & 7;
  const int i  = b0 >> 3;
  const int mt = i >> 1;
  const int nt = xc * 2 + (i & 1);

  const int srow = th >> 2;
  const int scol = ((th & 3) * 16) ^ (((th >> 5) & 1) << 5);
  const i8* gA0 = A + (size_t)(mt * 256 + srow) * KDIM + scol;
  const i8* gA1 = gA0 + (size_t)128 * KDIM;
  const i8* gB0 = B + (size_t)(nt * 256 + srow) * KDIM + scol;
  const i8* gB1 = gB0 + (size_t)128 * KDIM;

  const int ldsA0 = wave * 1024;
  const int ldsA1 = 8192 + wave * 1024;
  const int ldsB0 = 16384 + wave * 1024;
  const int ldsB1 = 24576 + wave * 1024;

#define STAGE_A(tt, ss) do {                                                    \
    __builtin_amdgcn_global_load_lds(                                           \
      (const __attribute__((address_space(1))) void*)(gA0 + (size_t)(tt) * BK), \
      (__attribute__((address_space(3))) void*)(lds + (ss) * 32768 + ldsA0), 16, 0, 0); \
    __builtin_amdgcn_global_load_lds(                                           \
      (const __attribute__((address_space(1))) void*)(gA1 + (size_t)(tt) * BK), \
      (__attribute__((address_space(3))) void*)(lds + (ss) * 32768 + ldsA1), 16, 0, 0); \
  } while (0)
#define STAGE_B(tt, ss) do {                                                    \
    __builtin_amdgcn_global_load_lds(                                           \
      (const __attribute__((address_space(1))) void*)(gB0 + (size_t)(tt) * BK), \
      (__attribute__((address_space(3))) void*)(lds + (ss) * 32768 + ldsB0), 16, 0, 0); \
    __builtin_amdgcn_global_load_lds(                                           \
      (const __attribute__((address_space(1))) void*)(gB1 + (size_t)(tt) * BK), \
      (__attribute__((address_space(3))) void*)(lds + (ss) * 32768 + ldsB1), 16, 0, 0); \
  } while (0)

  const int wm = wave >> 2;
  const int wn = wave & 3;
  const int laneRow = lane & 15;
  const int kByte   = (lane >> 4) << 4;
  const int swz     = ((lane >> 3) & 1) << 5;
  const int aOff = (((wm * 128 + laneRow) * 64 + kByte) ^ swz);
  const int bOff = (((wn * 64 + laneRow) * 64 + kByte) ^ swz) + 16384;

  i32x4 acc[8][4];
#pragma unroll
  for (int mi = 0; mi < 8; ++mi)
#pragma unroll
    for (int ni = 0; ni < 4; ++ni)
      acc[mi][ni] = i32x4{0, 0, 0, 0};

  STAGE_A(0, 0); STAGE_B(0, 0);
  STAGE_A(1, 1); STAGE_B(1, 1);
  asm volatile("s_waitcnt vmcnt(4)" ::: "memory");
  __builtin_amdgcn_sched_barrier(0);
  __builtin_amdgcn_s_barrier();

  i32x4 afA[4], afB[4], bf0[4], bf1[4];
  {
    const char* c0 = (const char*)lds;
#pragma unroll
    for (int ni = 0; ni < 4; ++ni)
      bf0[ni] = *(const i32x4*)(c0 + bOff + ni * 1024);
#pragma unroll
    for (int mi = 0; mi < 4; ++mi)
      afA[mi] = *(const i32x4*)(c0 + aOff + mi * 1024);
  }

#define TILE(t, BFC, BFN) do {                                                  \
    const char* cur = (const char*)lds + ((t) & 3) * 32768;                     \
    const char* nxt = (const char*)lds + (((t) + 1) & 3) * 32768;               \
    _Pragma("unroll")                                                           \
    for (int mi = 0; mi < 4; ++mi)                                              \
      afB[mi] = *(const i32x4*)(cur + aOff + 4096 + mi * 1024);                 \
    if ((t) + 2 < NKT) STAGE_A((t) + 2, ((t) + 2) & 3);                         \
    asm volatile("s_waitcnt lgkmcnt(4)" ::: "memory");                          \
    __builtin_amdgcn_sched_barrier(0);                                          \
    __builtin_amdgcn_s_setprio(1);                                              \
    _Pragma("unroll")                                                           \
    for (int mi = 0; mi < 4; ++mi)                                              \
      _Pragma("unroll")                                                         \
      for (int ni = 0; ni < 4; ++ni)                                            \
        acc[mi][ni] = __builtin_amdgcn_mfma_i32_16x16x64_i8(afA[mi], BFC[ni],   \
                                                            acc[mi][ni], 0, 0, 0); \
    __builtin_amdgcn_s_setprio(0);                                              \
    if ((t) + 1 < NKT) {                                                        \
      if ((t) + 2 < NKT) { asm volatile("s_waitcnt vmcnt(2)" ::: "memory"); }   \
      else               { asm volatile("s_waitcnt vmcnt(0)" ::: "memory"); }   \
      __builtin_amdgcn_sched_barrier(0);                                        \
      __builtin_amdgcn_s_barrier();                                             \
      _Pragma("unroll")                                                         \
      for (int ni = 0; ni < 4; ++ni)                                            \
        BFN[ni] = *(const i32x4*)(nxt + bOff + ni * 1024);                      \
      _Pragma("unroll")                                                         \
      for (int mi = 0; mi < 4; ++mi)                                            \
        afA[mi] = *(const i32x4*)(nxt + aOff + mi * 1024);                      \
      if ((t) + 2 < NKT) STAGE_B((t) + 2, ((t) + 2) & 3);                       \
      asm volatile("s_waitcnt lgkmcnt(8)" ::: "memory");                        \
      __builtin_amdgcn_sched_barrier(0);                                        \
    } else {                                                                    \
      asm volatile("s_waitcnt lgkmcnt(0)" ::: "memory");                        \
      __builtin_amdgcn_sched_barrier(0);                                        \
    }                                                                           \
    __builtin_amdgcn_s_setprio(1);                                              \
    _Pragma("unroll")                                                           \
    for (int mi = 0; mi < 4; ++mi)                                              \
      _Pragma("unroll")                                                         \
      for (int ni = 0; ni < 4; ++ni)                                            \
        acc[mi + 4][ni] = __builtin_amdgcn_mfma_i32_16x16x64_i8(afB[mi], BFC[ni], \
                                                            acc[mi + 4][ni], 0, 0, 0); \
    __builtin_amdgcn_s_setprio(0);                                              \
  } while (0)

  for (int t = 0; t < NKT; t += 2) {
    TILE(t,     bf0, bf1);
    TILE(t + 1, bf1, bf0);
  }
#undef TILE
#undef STAGE_A
#undef STAGE_B

  const int col0 = nt * 256 + wn * 64 + (lane & 15);
  const int row0 = mt * 256 + wm * 128 + ((lane >> 4) << 2);
  float xs[4][8];
#pragma unroll
  for (int mi = 0; mi < 8; ++mi)
#pragma unroll
    for (int r = 0; r < 4; ++r)
      xs[r][mi] = xscale[row0 + mi * 16 + r];
#pragma unroll
  for (int ni = 0; ni < 4; ++ni) {
    const float sc = s[col0 + ni * 16];
    const float bv = bias[col0 + ni * 16];
#pragma unroll
    for (int mi = 0; mi < 8; ++mi) {
      float* cp = C + (size_t)(row0 + mi * 16) * NDIM + col0 + ni * 16;
#pragma unroll
      for (int r = 0; r < 4; ++r)
        cp[(size_t)r * NDIM] = (float)acc[mi][ni][r] * (xs[r][mi] * sc) + bv;
    }
  }
}

// ---------------------------------------------------------------------------
extern "C" void kernel_launch(void* const* d_in, const int* in_sizes, int n_in,
                              void* d_out, int out_size, void* d_ws, size_t ws_size,
                              hipStream_t stream) {
  (void)in_sizes; (void)n_in; (void)out_size; (void)ws_size;
  const float* x    = (const float*)d_in[0];
  const int*   Q    = (const int*)d_in[1];
  const float* s    = (const float*)d_in[2];
  const float* bias = (const float*)d_in[3];
  float* out = (float*)d_out;

  i8*    xq     = (i8*)d_ws;
  i8*    W8     = xq + (size_t)TOKENS * KDIM;
  float* xscale = (float*)(W8 + (size_t)NDIM * KDIM);

  fused_aux<<<dim3(6144), dim3(256), 0, stream>>>(x, xq, xscale, Q, W8);
  gemm256_i8<<<dim3((TOKENS / 256) * (NDIM / 256)), dim3(512), 0, stream>>>(
      xq, W8, xscale, s, bias, out);
}